// Round 1
// baseline (490.744 us; speedup 1.0000x reference)
//
#include <hip/hip_runtime.h>
#include <hip/hip_bf16.h>
#include <hip/hip_fp16.h>
#include <math.h>

// MOSDecoder round 7:
//  - Decoder GEMM retiled 128x128 -> 256x256 (512 threads, 8 waves of 128x64),
//    LDS double-buffered (2 x (32KB A + 32KB B) = 128KB dynamic LDS) with
//    issue-early/drain-late pipeline: next K-tile's global_load_lds is issued
//    BEFORE the ds_read+MFMA phase, and the single __syncthreads per K-step
//    (vmcnt(0)+barrier) drains it after ~2200 cycles of MFMA cover the latency.
//    One barrier per K-step instead of two + exposed load latency.
//  - Grid 2000 = 8 XCD x 250, bijective swizzle: per-XCD set = full A (2MB) +
//    ~16 B v-tiles (2MB) ~= 4MB L2.
//  - Same MFMA shape / scales / epilogue math as round 6 (bit-identical output).

#define D_ 512
#define E_ 4
#define V_ 32000
#define L_ 1024
#define AROWS (L_ * E_)   // 4096

#define SA_ 0x7D7D7D7D    // e8m0 2^-2 (latent stored x4)
#define SB_ 0x7B7B7B7B    // e8m0 2^-4 (W_dec stored x16)

typedef __attribute__((ext_vector_type(8))) short s16x8;
typedef __attribute__((ext_vector_type(4))) float f32x4;
typedef __attribute__((ext_vector_type(2))) float f32x2;
typedef __attribute__((ext_vector_type(4))) int i32x4;
typedef __attribute__((ext_vector_type(8))) int i32x8;
typedef __attribute__((ext_vector_type(4))) unsigned int u32x4;
typedef const __attribute__((address_space(1))) char* gp1_t;
typedef __attribute__((address_space(3))) char* lp3_t;

__device__ __forceinline__ void gload_lds16(const void* g, void* l) {
  __builtin_amdgcn_global_load_lds((gp1_t)g, (lp3_t)l, 16, 0, 0);
}

// ================= fused prep =================
// [0,8000)      tcvt W_dec [512][32000] -> fp8 WdecT8 [32000][512] (x16)
// [8000,9024)   tcvt W_latent -> bf16 WlatT [2048][512]
// [9024,9536)   cvt hs -> bf16
// [9536,9792)   prior log-softmax
// [9792,9808)   zero S
#define PREP_DEC  8000
#define PREP_LAT  (PREP_DEC + 1024)
#define PREP_CVT  (PREP_LAT + 512)
#define PREP_PRI  (PREP_CVT + 256)
#define PREP_TOT  (PREP_PRI + 16)

__global__ __launch_bounds__(256) void prep_kernel(
    const float* __restrict__ hs, const float* __restrict__ W_prior,
    const float* __restrict__ b_prior, const float* __restrict__ W_latent,
    const float* __restrict__ W_dec,
    __hip_bfloat16* __restrict__ hs_bf, __hip_bfloat16* __restrict__ WlatT,
    unsigned char* __restrict__ WdecT8, float* __restrict__ log_coef,
    float* __restrict__ S) {
  __shared__ float tileS[64 * 33];
  const int b = blockIdx.x;
  const int tid = threadIdx.x;

  if (b < PREP_DEC) {
    // W_dec [512][32000] -> WdecT8 [32000][512]; tile 64 d-rows x 32 v-cols.
    const int vb = (b % 1000) * 32;
    const int db = (b / 1000) * 64;
    {
      const int r = tid >> 2, c0 = (tid & 3) * 8;
      const float* src = W_dec + (size_t)(db + r) * V_ + vb + c0;
      float4 a0 = *(const float4*)src;
      float4 a1 = *(const float4*)(src + 4);
      float* t = &tileS[r * 33 + c0];
      t[0] = a0.x; t[1] = a0.y; t[2] = a0.z; t[3] = a0.w;
      t[4] = a1.x; t[5] = a1.y; t[6] = a1.z; t[7] = a1.w;
    }
    __syncthreads();
    {
      const int vr = tid >> 3, d0 = (tid & 7) * 8;
      float t8[8];
      #pragma unroll
      for (int j = 0; j < 8; ++j) t8[j] = tileS[(d0 + j) * 33 + vr] * 16.f;
      unsigned int u0 = 0, u1 = 0;
      u0 = __builtin_amdgcn_cvt_pk_fp8_f32(t8[0], t8[1], u0, false);
      u0 = __builtin_amdgcn_cvt_pk_fp8_f32(t8[2], t8[3], u0, true);
      u1 = __builtin_amdgcn_cvt_pk_fp8_f32(t8[4], t8[5], u1, false);
      u1 = __builtin_amdgcn_cvt_pk_fp8_f32(t8[6], t8[7], u1, true);
      uint2 uu = {u0, u1};
      *(uint2*)&WdecT8[(size_t)(vb + vr) * D_ + db + d0] = uu;
    }
  } else if (b < PREP_LAT) {
    const int bb = b - PREP_DEC;
    const int cb = (bb & 63) * 32, rb = (bb >> 6) * 32;
    const int C = E_ * D_, R = D_;
    const int tx = tid & 31, ty = tid >> 5;  // 32x8
    #pragma unroll
    for (int j = 0; j < 32; j += 8)
      tileS[(ty + j) * 33 + tx] = W_latent[(size_t)(rb + ty + j) * C + cb + tx];
    __syncthreads();
    #pragma unroll
    for (int j = 0; j < 32; j += 8)
      WlatT[(size_t)(cb + ty + j) * R + rb + tx] = __float2bfloat16(tileS[tx * 33 + ty + j]);
  } else if (b < PREP_CVT) {
    int i = ((b - PREP_LAT) * 256 + tid) * 4;
    float4 v = *(const float4*)(hs + i);
    hs_bf[i + 0] = __float2bfloat16(v.x);
    hs_bf[i + 1] = __float2bfloat16(v.y);
    hs_bf[i + 2] = __float2bfloat16(v.z);
    hs_bf[i + 3] = __float2bfloat16(v.w);
  } else if (b < PREP_PRI) {
    int t = (b - PREP_CVT) * 4 + (tid >> 6);
    int lane = tid & 63;
    float a0 = 0.f, a1 = 0.f, a2 = 0.f, a3 = 0.f;
    for (int d = lane; d < D_; d += 64) {
      float h = hs[t * D_ + d];
      float4 w = ((const float4*)W_prior)[d];
      a0 += h * w.x; a1 += h * w.y; a2 += h * w.z; a3 += h * w.w;
    }
    #pragma unroll
    for (int off = 32; off > 0; off >>= 1) {
      a0 += __shfl_xor(a0, off);
      a1 += __shfl_xor(a1, off);
      a2 += __shfl_xor(a2, off);
      a3 += __shfl_xor(a3, off);
    }
    a0 += b_prior[0]; a1 += b_prior[1]; a2 += b_prior[2]; a3 += b_prior[3];
    float mx = fmaxf(fmaxf(a0, a1), fmaxf(a2, a3));
    float ls = mx + logf(expf(a0 - mx) + expf(a1 - mx) + expf(a2 - mx) + expf(a3 - mx));
    if (lane == 0) {
      log_coef[t * 4 + 0] = a0 - ls;
      log_coef[t * 4 + 1] = a1 - ls;
      log_coef[t * 4 + 2] = a2 - ls;
      log_coef[t * 4 + 3] = a3 - ls;
    }
  } else {
    S[(b - PREP_PRI) * 256 + tid] = 0.f;
  }
}

// ---- q = exp(log_coef)/S (fallback path only) ----
__global__ void qk_kernel(const float* __restrict__ log_coef, const float* __restrict__ S,
                          float* __restrict__ q) {
  int i = blockIdx.x * blockDim.x + threadIdx.x;
  if (i < AROWS) q[i] = __expf(log_coef[i]) / S[i];
}

// ---- latent = fp8(4*tanh(hs @ W_latent + b)) -> [L][E*D] == [4096][512] ----
__global__ __launch_bounds__(256, 2) void latent_gemm(
    const __hip_bfloat16* __restrict__ Abf, const __hip_bfloat16* __restrict__ BT,
    const float* __restrict__ b_latent, unsigned char* __restrict__ latent8) {
  __shared__ short As[128 * 32];
  __shared__ short Bs[128 * 32];
  const int tid = threadIdx.x;
  const int wave = tid >> 6, lane = tid & 63;
  const int wm = wave >> 1, wn = wave & 1;
  const int m0 = blockIdx.y * 128;
  const int n0 = blockIdx.x * 128;
  const int lrow = lane & 15;
  const int kgrp = lane >> 4;
  const int srow = wave * 16 + (lane >> 2);
  const int scol = (lane & 3) * 8;

  f32x4 acc[4][4];
  #pragma unroll
  for (int mt = 0; mt < 4; ++mt)
    #pragma unroll
    for (int nt = 0; nt < 4; ++nt) acc[mt][nt] = f32x4{0.f, 0.f, 0.f, 0.f};

  for (int kt = 0; kt < 16; ++kt) {
    const int k0 = kt * 32;
    #pragma unroll
    for (int j = 0; j < 2; ++j) {
      const int row = j * 64 + srow;
      gload_lds16(Abf + (size_t)(m0 + row) * D_ + k0 + scol, &As[(j * 256 + wave * 64) * 8]);
      gload_lds16(BT + (size_t)(n0 + row) * D_ + k0 + scol, &Bs[(j * 256 + wave * 64) * 8]);
    }
    __syncthreads();
    s16x8 af[4], bfr[4];
    #pragma unroll
    for (int mt = 0; mt < 4; ++mt) af[mt] = *(const s16x8*)&As[(wm * 64 + mt * 16 + lrow) * 32 + kgrp * 8];
    #pragma unroll
    for (int nt = 0; nt < 4; ++nt) bfr[nt] = *(const s16x8*)&Bs[(wn * 64 + nt * 16 + lrow) * 32 + kgrp * 8];
    #pragma unroll
    for (int mt = 0; mt < 4; ++mt)
      #pragma unroll
      for (int nt = 0; nt < 4; ++nt)
        acc[mt][nt] = __builtin_amdgcn_mfma_f32_16x16x32_bf16(af[mt], bfr[nt], acc[mt][nt], 0, 0, 0);
    __syncthreads();
  }

  float blat[4];
  #pragma unroll
  for (int nt = 0; nt < 4; ++nt) blat[nt] = b_latent[n0 + wn * 64 + nt * 16 + lrow];
  #pragma unroll
  for (int mt = 0; mt < 4; ++mt)
    #pragma unroll
    for (int r = 0; r < 4; ++r) {
      const int row = m0 + wm * 64 + mt * 16 + kgrp * 4 + r;  // token
      #pragma unroll
      for (int nt = 0; nt < 4; ++nt) {
        const int col = n0 + wn * 64 + nt * 16 + lrow;
        float v = tanhf(acc[mt][nt][r] + blat[nt]) * 4.f;     // x4: e4m3 + HW scale 2^-2
        int u = __builtin_amdgcn_cvt_pk_fp8_f32(v, v, 0, false);
        latent8[(size_t)row * (E_ * D_) + col] = (unsigned char)(u & 0xff);
      }
    }
}

// ---- decoder GEMM (MX-fp8, K=128), 256x256 tile, 8 waves, dbuf pipeline.
//      MODE 1: S only. MODE 2: out directly. MODE 3: S + p=exp packed fp8. ----
template <int MODE>
__global__ __launch_bounds__(512, 2) void mos_gemm(
    const unsigned char* __restrict__ A8,      // [4096][512] fp8 (x4), row = l*4+e
    const unsigned char* __restrict__ W8,      // [32000][512] fp8 (x16)
    const float* __restrict__ b_dec,
    const float* __restrict__ q,               // [4096] (MODE 2)
    float* __restrict__ S,                     // [4096] (MODE 1/3)
    float* __restrict__ out,                   // [1024][32000] (MODE 2)
    unsigned int* __restrict__ pbuf) {         // [1024][32000] (MODE 3)
  extern __shared__ __attribute__((aligned(16))) char smem[];
  // Grid = 2000 = 8 XCDs x 250 -> bijective XCD swizzle; per-XCD working set:
  // full A panel (2MB) + ~15.6 v-tiles of B (2MB) ~= one XCD's 4MB L2.
  const int bid = blockIdx.x;
  const int wgid = (bid & 7) * 250 + (bid >> 3);
  const int m0 = (wgid & 15) * 256;
  const int v0 = (wgid >> 4) * 256;

  const int tid = threadIdx.x;
  const int wave = tid >> 6, lane = tid & 63;
  const int wm = wave >> 2, wn = wave & 3;   // 2M x 4N waves; wave tile 128x64
  const int lrow = lane & 15;
  const int kgrp = lane >> 4;

  char* const As0 = smem;                    // [256][128] fp8
  char* const Bs0 = smem + 32768;
  char* const As1 = smem + 65536;
  char* const Bs1 = smem + 98304;

  const int srow = tid >> 3;                 // staging row 0..63 (per j-group of 64)
  const int schunk = tid & 7;                // 16B chunk within 128B row
  const int ldsoff = wave * 1024;            // wave-uniform LDS dest base offset

  f32x4 acc[8][4];
  #pragma unroll
  for (int mt = 0; mt < 8; ++mt)
    #pragma unroll
    for (int nt = 0; nt < 4; ++nt) acc[mt][nt] = f32x4{0.f, 0.f, 0.f, 0.f};

  // stage one 256x128 A-tile + 256x128 B-tile (64KB) via global_load_lds:
  // LDS dest linear (base+lane*16); XOR chunk-swizzle applied on the GLOBAL side.
  auto stage = [&](char* bA, char* bB, int kb) {
    #pragma unroll
    for (int j = 0; j < 4; ++j) {
      const int row = j * 64 + srow;
      const int sc = (schunk ^ (row & 7)) * 16;
      gload_lds16(A8 + (size_t)(m0 + row) * D_ + kb + sc, bA + j * 8192 + ldsoff);
      gload_lds16(W8 + (size_t)(v0 + row) * D_ + kb + sc, bB + j * 8192 + ldsoff);
    }
  };

  // one K=128 step: 8x4 MFMAs from the given buffers
  auto kstep = [&](const char* bA, const char* bB) {
    const int s = lrow & 7;
    i32x8 bfr[4];
    #pragma unroll
    for (int nt = 0; nt < 4; ++nt) {
      const int row = wn * 64 + nt * 16 + lrow;
      i32x4 lo = *(const i32x4*)(bB + row * 128 + (((kgrp * 2) ^ s) * 16));
      i32x4 hi = *(const i32x4*)(bB + row * 128 + (((kgrp * 2 + 1) ^ s) * 16));
      bfr[nt] = __builtin_shufflevector(lo, hi, 0, 1, 2, 3, 4, 5, 6, 7);
    }
    __builtin_amdgcn_s_setprio(1);
    #pragma unroll
    for (int mt = 0; mt < 8; ++mt) {
      const int row = wm * 128 + mt * 16 + lrow;
      i32x4 lo = *(const i32x4*)(bA + row * 128 + (((kgrp * 2) ^ s) * 16));
      i32x4 hi = *(const i32x4*)(bA + row * 128 + (((kgrp * 2 + 1) ^ s) * 16));
      i32x8 a = __builtin_shufflevector(lo, hi, 0, 1, 2, 3, 4, 5, 6, 7);
      #pragma unroll
      for (int nt = 0; nt < 4; ++nt)
        acc[mt][nt] = __builtin_amdgcn_mfma_scale_f32_16x16x128_f8f6f4(
            a, bfr[nt], acc[mt][nt], 0, 0, 0, SA_, 0, SB_);
    }
    __builtin_amdgcn_s_setprio(0);
  };

  // Pipeline: issue-early / drain-late; ONE __syncthreads per K-step.
  // The implicit vmcnt(0) at each barrier drains loads that were issued
  // BEFORE ~2200 cycles of MFMA -> latency hidden.
  stage(As0, Bs0, 0);
  __syncthreads();
  stage(As1, Bs1, 128);
  kstep(As0, Bs0);
  __syncthreads();          // As1/Bs1 ready; As0/Bs0 reads done
  stage(As0, Bs0, 256);
  kstep(As1, Bs1);
  __syncthreads();
  stage(As1, Bs1, 384);
  kstep(As0, Bs0);
  __syncthreads();
  kstep(As1, Bs1);

  float bdec[4];
  #pragma unroll
  for (int nt = 0; nt < 4; ++nt) bdec[nt] = b_dec[v0 + wn * 64 + nt * 16 + lrow];

  if constexpr (MODE == 1 || MODE == 3) {
    #pragma unroll
    for (int mt = 0; mt < 8; ++mt) {
      const int row4 = m0 + wm * 128 + mt * 16 + kgrp * 4;
      const int token = row4 >> 2;
      float p0 = 0.f, p1 = 0.f, p2 = 0.f, p3 = 0.f;
      #pragma unroll
      for (int nt = 0; nt < 4; ++nt) {
        float e0 = __expf(acc[mt][nt][0] + bdec[nt]);
        float e1 = __expf(acc[mt][nt][1] + bdec[nt]);
        float e2 = __expf(acc[mt][nt][2] + bdec[nt]);
        float e3 = __expf(acc[mt][nt][3] + bdec[nt]);
        p0 += e0; p1 += e1; p2 += e2; p3 += e3;
        if constexpr (MODE == 3) {
          const int v = v0 + wn * 64 + nt * 16 + lrow;
          int u = 0;
          u = __builtin_amdgcn_cvt_pk_fp8_f32(e0, e1, u, false);
          u = __builtin_amdgcn_cvt_pk_fp8_f32(e2, e3, u, true);
          __builtin_nontemporal_store((unsigned int)u, &pbuf[(size_t)token * V_ + v]);
        }
      }
      #pragma unroll
      for (int off = 1; off < 16; off <<= 1) {
        p0 += __shfl_xor(p0, off);
        p1 += __shfl_xor(p1, off);
        p2 += __shfl_xor(p2, off);
        p3 += __shfl_xor(p3, off);
      }
      if (lrow == 0) {
        atomicAdd(&S[row4 + 0], p0);
        atomicAdd(&S[row4 + 1], p1);
        atomicAdd(&S[row4 + 2], p2);
        atomicAdd(&S[row4 + 3], p3);
      }
    }
  } else {  // MODE == 2
    #pragma unroll
    for (int mt = 0; mt < 8; ++mt) {
      const int row4 = m0 + wm * 128 + mt * 16 + kgrp * 4;
      const float4 qv = *(const float4*)&q[row4];
      const int token = row4 >> 2;
      #pragma unroll
      for (int nt = 0; nt < 4; ++nt) {
        float v = qv.x * __expf(acc[mt][nt][0] + bdec[nt]) +
                  qv.y * __expf(acc[mt][nt][1] + bdec[nt]) +
                  qv.z * __expf(acc[mt][nt][2] + bdec[nt]) +
                  qv.w * __expf(acc[mt][nt][3] + bdec[nt]);
        out[(size_t)token * V_ + v0 + wn * 64 + nt * 16 + lrow] = __logf(v);
      }
    }
  }
}

// ---- combine: out[t][v] = log(sum_e q_e * p8[t][v][e]) ----
__global__ __launch_bounds__(256) void combine_kernel(
    const unsigned int* __restrict__ pbuf,
    const float* __restrict__ lc, const float* __restrict__ S,
    float* __restrict__ out) {
  const int t = blockIdx.y;
  const int v = blockIdx.x * 1024 + threadIdx.x * 4;
  if (v >= V_) return;
  const float4 lcv = ((const float4*)lc)[t];
  const float4 Sv = ((const float4*)S)[t];
  const float q0 = __expf(lcv.x) / Sv.x;
  const float q1 = __expf(lcv.y) / Sv.y;
  const float q2 = __expf(lcv.z) / Sv.z;
  const float q3 = __expf(lcv.w) / Sv.w;
  u32x4 u = __builtin_nontemporal_load((const u32x4*)(pbuf + (size_t)t * V_ + v));
  float4 o;
  #pragma unroll
  for (int j = 0; j < 4; ++j) {
    unsigned int w = u[j];
    f32x2 lo = __builtin_amdgcn_cvt_pk_f32_fp8(w, false);
    f32x2 hi = __builtin_amdgcn_cvt_pk_f32_fp8(w, true);
    float s = q0 * lo.x + q1 * lo.y + q2 * hi.x + q3 * hi.y;
    ((float*)&o)[j] = __logf(s);
  }
  *(float4*)&out[(size_t)t * V_ + v] = o;
}

extern "C" void kernel_launch(void* const* d_in, const int* in_sizes, int n_in,
                              void* d_out, int out_size, void* d_ws, size_t ws_size,
                              hipStream_t stream) {
  const float* hs       = (const float*)d_in[0];
  const float* W_prior  = (const float*)d_in[1];
  const float* b_prior  = (const float*)d_in[2];
  const float* W_latent = (const float*)d_in[3];
  const float* b_latent = (const float*)d_in[4];
  const float* W_dec    = (const float*)d_in[5];
  const float* b_dec    = (const float*)d_in[6];
  float* out = (float*)d_out;

  char* ws = (char*)d_ws;
  __hip_bfloat16* hs_bf   = (__hip_bfloat16*)(ws);                    // 1 MB
  __hip_bfloat16* WlatT   = (__hip_bfloat16*)(ws + (1u << 20));       // 2 MB
  unsigned char*  latent8 = (unsigned char*)(ws + 3u * (1u << 20));   // 2 MB [4096][512]
  unsigned char*  WdecT8  = (unsigned char*)(ws + 5u * (1u << 20));   // 16.4 MB [32000][512]
  float* log_coef = (float*)(ws + 22u * (1u << 20));                  // 16 KB
  float* S = log_coef + AROWS;                                        // 16 KB
  float* q = S + AROWS;                                               // 16 KB
  unsigned int* pbuf = (unsigned int*)(ws + 23u * (1u << 20));        // 131 MB

  const size_t needA = 23u * (1u << 20) + (size_t)L_ * V_ * 4;
  const bool pathA = ws_size >= needA;

  static bool attr_done = false;
  if (!attr_done) {
    hipFuncSetAttribute((const void*)&mos_gemm<1>,
                        hipFuncAttributeMaxDynamicSharedMemorySize, 131072);
    hipFuncSetAttribute((const void*)&mos_gemm<2>,
                        hipFuncAttributeMaxDynamicSharedMemorySize, 131072);
    hipFuncSetAttribute((const void*)&mos_gemm<3>,
                        hipFuncAttributeMaxDynamicSharedMemorySize, 131072);
    attr_done = true;
  }

  prep_kernel<<<PREP_TOT, 256, 0, stream>>>(hs, W_prior, b_prior, W_latent, W_dec,
                                            hs_bf, WlatT, WdecT8, log_coef, S);
  latent_gemm<<<dim3((E_ * D_) / 128, L_ / 128), 256, 0, stream>>>(hs_bf, WlatT, b_latent, latent8);

  if (pathA) {
    mos_gemm<3><<<2000, 512, 131072, stream>>>(latent8, WdecT8, b_dec, nullptr, S, nullptr, pbuf);
    combine_kernel<<<dim3(32, L_), 256, 0, stream>>>(pbuf, log_coef, S, out);
  } else {
    mos_gemm<1><<<2000, 512, 131072, stream>>>(latent8, WdecT8, b_dec, nullptr, S, nullptr, nullptr);
    qk_kernel<<<(AROWS + 255) / 256, 256, 0, stream>>>(log_coef, S, q);
    mos_gemm<2><<<2000, 512, 131072, stream>>>(latent8, WdecT8, b_dec, q, nullptr, out, nullptr);
  }
}

// Round 2
// 351.330 us; speedup vs baseline: 1.3968x; 1.3968x over previous
//
#include <hip/hip_runtime.h>
#include <hip/hip_bf16.h>
#include <hip/hip_fp16.h>
#include <math.h>

// MOSDecoder round 8:
//  - Revert to round-6's 128x128 decoder-GEMM tile/grid/swizzle (verified low
//    HBM traffic: FETCH ~20MB), change ONLY the K-loop structure:
//    double-buffered LDS (4x16KB = 64KB static, still 2 blocks/CU) with ONE
//    barrier per K-step, issue-early/drain-late: stage(t+1) issued before
//    kstep(t)'s ds_read+MFMA so the barrier's vmcnt(0) drain is covered.
//  - s_setprio(1) around MFMA cluster (2 blocks/CU -> phase diversity).
//  - Round 7 post-mortem: 256^2 + 128KB LDS (1 block/CU) exploded HBM traffic
//    5.8x (FETCH 20->364MB, WRITE 172->757MB) and went HBM-bound; unbundled.

#define D_ 512
#define E_ 4
#define V_ 32000
#define L_ 1024
#define AROWS (L_ * E_)   // 4096

#define SA_ 0x7D7D7D7D    // e8m0 2^-2 (latent stored x4)
#define SB_ 0x7B7B7B7B    // e8m0 2^-4 (W_dec stored x16)

typedef __attribute__((ext_vector_type(8))) short s16x8;
typedef __attribute__((ext_vector_type(4))) float f32x4;
typedef __attribute__((ext_vector_type(2))) float f32x2;
typedef __attribute__((ext_vector_type(4))) int i32x4;
typedef __attribute__((ext_vector_type(8))) int i32x8;
typedef __attribute__((ext_vector_type(4))) unsigned int u32x4;
typedef const __attribute__((address_space(1))) char* gp1_t;
typedef __attribute__((address_space(3))) char* lp3_t;

__device__ __forceinline__ void gload_lds16(const void* g, void* l) {
  __builtin_amdgcn_global_load_lds((gp1_t)g, (lp3_t)l, 16, 0, 0);
}

// ================= fused prep =================
// [0,8000)      tcvt W_dec [512][32000] -> fp8 WdecT8 [32000][512] (x16)
// [8000,9024)   tcvt W_latent -> bf16 WlatT [2048][512]
// [9024,9536)   cvt hs -> bf16
// [9536,9792)   prior log-softmax
// [9792,9808)   zero S
#define PREP_DEC  8000
#define PREP_LAT  (PREP_DEC + 1024)
#define PREP_CVT  (PREP_LAT + 512)
#define PREP_PRI  (PREP_CVT + 256)
#define PREP_TOT  (PREP_PRI + 16)

__global__ __launch_bounds__(256) void prep_kernel(
    const float* __restrict__ hs, const float* __restrict__ W_prior,
    const float* __restrict__ b_prior, const float* __restrict__ W_latent,
    const float* __restrict__ W_dec,
    __hip_bfloat16* __restrict__ hs_bf, __hip_bfloat16* __restrict__ WlatT,
    unsigned char* __restrict__ WdecT8, float* __restrict__ log_coef,
    float* __restrict__ S) {
  __shared__ float tileS[64 * 33];
  const int b = blockIdx.x;
  const int tid = threadIdx.x;

  if (b < PREP_DEC) {
    // W_dec [512][32000] -> WdecT8 [32000][512]; tile 64 d-rows x 32 v-cols.
    const int vb = (b % 1000) * 32;
    const int db = (b / 1000) * 64;
    {
      const int r = tid >> 2, c0 = (tid & 3) * 8;
      const float* src = W_dec + (size_t)(db + r) * V_ + vb + c0;
      float4 a0 = *(const float4*)src;
      float4 a1 = *(const float4*)(src + 4);
      float* t = &tileS[r * 33 + c0];
      t[0] = a0.x; t[1] = a0.y; t[2] = a0.z; t[3] = a0.w;
      t[4] = a1.x; t[5] = a1.y; t[6] = a1.z; t[7] = a1.w;
    }
    __syncthreads();
    {
      const int vr = tid >> 3, d0 = (tid & 7) * 8;
      float t8[8];
      #pragma unroll
      for (int j = 0; j < 8; ++j) t8[j] = tileS[(d0 + j) * 33 + vr] * 16.f;
      unsigned int u0 = 0, u1 = 0;
      u0 = __builtin_amdgcn_cvt_pk_fp8_f32(t8[0], t8[1], u0, false);
      u0 = __builtin_amdgcn_cvt_pk_fp8_f32(t8[2], t8[3], u0, true);
      u1 = __builtin_amdgcn_cvt_pk_fp8_f32(t8[4], t8[5], u1, false);
      u1 = __builtin_amdgcn_cvt_pk_fp8_f32(t8[6], t8[7], u1, true);
      uint2 uu = {u0, u1};
      *(uint2*)&WdecT8[(size_t)(vb + vr) * D_ + db + d0] = uu;
    }
  } else if (b < PREP_LAT) {
    const int bb = b - PREP_DEC;
    const int cb = (bb & 63) * 32, rb = (bb >> 6) * 32;
    const int C = E_ * D_, R = D_;
    const int tx = tid & 31, ty = tid >> 5;  // 32x8
    #pragma unroll
    for (int j = 0; j < 32; j += 8)
      tileS[(ty + j) * 33 + tx] = W_latent[(size_t)(rb + ty + j) * C + cb + tx];
    __syncthreads();
    #pragma unroll
    for (int j = 0; j < 32; j += 8)
      WlatT[(size_t)(cb + ty + j) * R + rb + tx] = __float2bfloat16(tileS[tx * 33 + ty + j]);
  } else if (b < PREP_CVT) {
    int i = ((b - PREP_LAT) * 256 + tid) * 4;
    float4 v = *(const float4*)(hs + i);
    hs_bf[i + 0] = __float2bfloat16(v.x);
    hs_bf[i + 1] = __float2bfloat16(v.y);
    hs_bf[i + 2] = __float2bfloat16(v.z);
    hs_bf[i + 3] = __float2bfloat16(v.w);
  } else if (b < PREP_PRI) {
    int t = (b - PREP_CVT) * 4 + (tid >> 6);
    int lane = tid & 63;
    float a0 = 0.f, a1 = 0.f, a2 = 0.f, a3 = 0.f;
    for (int d = lane; d < D_; d += 64) {
      float h = hs[t * D_ + d];
      float4 w = ((const float4*)W_prior)[d];
      a0 += h * w.x; a1 += h * w.y; a2 += h * w.z; a3 += h * w.w;
    }
    #pragma unroll
    for (int off = 32; off > 0; off >>= 1) {
      a0 += __shfl_xor(a0, off);
      a1 += __shfl_xor(a1, off);
      a2 += __shfl_xor(a2, off);
      a3 += __shfl_xor(a3, off);
    }
    a0 += b_prior[0]; a1 += b_prior[1]; a2 += b_prior[2]; a3 += b_prior[3];
    float mx = fmaxf(fmaxf(a0, a1), fmaxf(a2, a3));
    float ls = mx + logf(expf(a0 - mx) + expf(a1 - mx) + expf(a2 - mx) + expf(a3 - mx));
    if (lane == 0) {
      log_coef[t * 4 + 0] = a0 - ls;
      log_coef[t * 4 + 1] = a1 - ls;
      log_coef[t * 4 + 2] = a2 - ls;
      log_coef[t * 4 + 3] = a3 - ls;
    }
  } else {
    S[(b - PREP_PRI) * 256 + tid] = 0.f;
  }
}

// ---- q = exp(log_coef)/S (fallback path only) ----
__global__ void qk_kernel(const float* __restrict__ log_coef, const float* __restrict__ S,
                          float* __restrict__ q) {
  int i = blockIdx.x * blockDim.x + threadIdx.x;
  if (i < AROWS) q[i] = __expf(log_coef[i]) / S[i];
}

// ---- latent = fp8(4*tanh(hs @ W_latent + b)) -> [L][E*D] == [4096][512] ----
__global__ __launch_bounds__(256, 2) void latent_gemm(
    const __hip_bfloat16* __restrict__ Abf, const __hip_bfloat16* __restrict__ BT,
    const float* __restrict__ b_latent, unsigned char* __restrict__ latent8) {
  __shared__ short As[128 * 32];
  __shared__ short Bs[128 * 32];
  const int tid = threadIdx.x;
  const int wave = tid >> 6, lane = tid & 63;
  const int wm = wave >> 1, wn = wave & 1;
  const int m0 = blockIdx.y * 128;
  const int n0 = blockIdx.x * 128;
  const int lrow = lane & 15;
  const int kgrp = lane >> 4;
  const int srow = wave * 16 + (lane >> 2);
  const int scol = (lane & 3) * 8;

  f32x4 acc[4][4];
  #pragma unroll
  for (int mt = 0; mt < 4; ++mt)
    #pragma unroll
    for (int nt = 0; nt < 4; ++nt) acc[mt][nt] = f32x4{0.f, 0.f, 0.f, 0.f};

  for (int kt = 0; kt < 16; ++kt) {
    const int k0 = kt * 32;
    #pragma unroll
    for (int j = 0; j < 2; ++j) {
      const int row = j * 64 + srow;
      gload_lds16(Abf + (size_t)(m0 + row) * D_ + k0 + scol, &As[(j * 256 + wave * 64) * 8]);
      gload_lds16(BT + (size_t)(n0 + row) * D_ + k0 + scol, &Bs[(j * 256 + wave * 64) * 8]);
    }
    __syncthreads();
    s16x8 af[4], bfr[4];
    #pragma unroll
    for (int mt = 0; mt < 4; ++mt) af[mt] = *(const s16x8*)&As[(wm * 64 + mt * 16 + lrow) * 32 + kgrp * 8];
    #pragma unroll
    for (int nt = 0; nt < 4; ++nt) bfr[nt] = *(const s16x8*)&Bs[(wn * 64 + nt * 16 + lrow) * 32 + kgrp * 8];
    #pragma unroll
    for (int mt = 0; mt < 4; ++mt)
      #pragma unroll
      for (int nt = 0; nt < 4; ++nt)
        acc[mt][nt] = __builtin_amdgcn_mfma_f32_16x16x32_bf16(af[mt], bfr[nt], acc[mt][nt], 0, 0, 0);
    __syncthreads();
  }

  float blat[4];
  #pragma unroll
  for (int nt = 0; nt < 4; ++nt) blat[nt] = b_latent[n0 + wn * 64 + nt * 16 + lrow];
  #pragma unroll
  for (int mt = 0; mt < 4; ++mt)
    #pragma unroll
    for (int r = 0; r < 4; ++r) {
      const int row = m0 + wm * 64 + mt * 16 + kgrp * 4 + r;  // token
      #pragma unroll
      for (int nt = 0; nt < 4; ++nt) {
        const int col = n0 + wn * 64 + nt * 16 + lrow;
        float v = tanhf(acc[mt][nt][r] + blat[nt]) * 4.f;     // x4: e4m3 + HW scale 2^-2
        int u = __builtin_amdgcn_cvt_pk_fp8_f32(v, v, 0, false);
        latent8[(size_t)row * (E_ * D_) + col] = (unsigned char)(u & 0xff);
      }
    }
}

// ---- decoder GEMM (MX-fp8, K=128), 128x128 tile, double-buffered LDS,
//      one barrier per K-step. MODE 1: S only. MODE 2: out directly.
//      MODE 3: S + store p=exp(logit+b) packed 4x e4m3. ----
template <int MODE>
__global__ __launch_bounds__(256, 2) void mos_gemm(
    const unsigned char* __restrict__ A8,      // [4096][512] fp8 (x4), row = l*4+e
    const unsigned char* __restrict__ W8,      // [32000][512] fp8 (x16)
    const float* __restrict__ b_dec,
    const float* __restrict__ q,               // [4096] (MODE 2)
    float* __restrict__ S,                     // [4096] (MODE 1/3)
    float* __restrict__ out,                   // [1024][32000] (MODE 2)
    unsigned int* __restrict__ pbuf) {         // [1024][32000] (MODE 3)
  const int bid = blockIdx.x;
  const int xcd = bid & 7;
  const int idx = bid >> 3;
  const int mg = xcd >> 2;
  const int vg = xcd & 3;
  const int vt = vg * 63 + (idx >> 4);
  const int mtile = mg * 16 + (idx & 15);
  if (vt >= V_ / 128) return;
  const int m0 = mtile * 128;
  const int v0 = vt * 128;

  __shared__ __attribute__((aligned(16))) unsigned char As0[128 * 128];
  __shared__ __attribute__((aligned(16))) unsigned char Bs0[128 * 128];
  __shared__ __attribute__((aligned(16))) unsigned char As1[128 * 128];
  __shared__ __attribute__((aligned(16))) unsigned char Bs1[128 * 128];

  const int tid = threadIdx.x;
  const int wave = tid >> 6, lane = tid & 63;
  const int wm = wave >> 1, wn = wave & 1;
  const int lrow = lane & 15;
  const int kgrp = lane >> 4;
  const int srow8 = wave * 8 + (lane >> 3);      // staging row within 32-row group
  const int schunk = lane & 7;                   // 16-B chunk within 128-B row

  float bdec[4];
  #pragma unroll
  for (int nt = 0; nt < 4; ++nt) bdec[nt] = b_dec[v0 + wn * 64 + nt * 16 + lrow];

  f32x4 acc[4][4];
  #pragma unroll
  for (int mt = 0; mt < 4; ++mt)
    #pragma unroll
    for (int nt = 0; nt < 4; ++nt) acc[mt][nt] = f32x4{0.f, 0.f, 0.f, 0.f};

  // stage one K=128 tile (16KB A + 16KB B) via global_load_lds:
  // LDS dest linear (wave-uniform base + lane*16); XOR chunk swizzle applied
  // on the GLOBAL source address so reads can be bank-spread.
  auto stage = [&](unsigned char* bA, unsigned char* bB, int kb) {
    #pragma unroll
    for (int j = 0; j < 4; ++j) {
      const int row = j * 32 + srow8;
      const int sc = (schunk ^ (row & 7)) * 16;
      gload_lds16(A8 + (size_t)(m0 + row) * D_ + kb + sc, bA + (j * 32 + wave * 8) * 128);
      gload_lds16(W8 + (size_t)(v0 + row) * D_ + kb + sc, bB + (j * 32 + wave * 8) * 128);
    }
  };

  // one K=128 step: 4x4 MFMAs from the given buffers
  auto kstep = [&](const unsigned char* bA, const unsigned char* bB) {
    const int s = lrow & 7;
    i32x8 bfr[4];
    #pragma unroll
    for (int nt = 0; nt < 4; ++nt) {
      const int row = wn * 64 + nt * 16 + lrow;
      i32x4 lo = *(const i32x4*)&bB[row * 128 + (((kgrp * 2) ^ s) * 16)];
      i32x4 hi = *(const i32x4*)&bB[row * 128 + (((kgrp * 2 + 1) ^ s) * 16)];
      bfr[nt] = __builtin_shufflevector(lo, hi, 0, 1, 2, 3, 4, 5, 6, 7);
    }
    __builtin_amdgcn_s_setprio(1);
    #pragma unroll
    for (int mt = 0; mt < 4; ++mt) {
      const int row = wm * 64 + mt * 16 + lrow;
      i32x4 lo = *(const i32x4*)&bA[row * 128 + (((kgrp * 2) ^ s) * 16)];
      i32x4 hi = *(const i32x4*)&bA[row * 128 + (((kgrp * 2 + 1) ^ s) * 16)];
      i32x8 a = __builtin_shufflevector(lo, hi, 0, 1, 2, 3, 4, 5, 6, 7);
      #pragma unroll
      for (int nt = 0; nt < 4; ++nt)
        acc[mt][nt] = __builtin_amdgcn_mfma_scale_f32_16x16x128_f8f6f4(
            a, bfr[nt], acc[mt][nt], 0, 0, 0, SA_, 0, SB_);
    }
    __builtin_amdgcn_s_setprio(0);
  };

  // Double-buffered pipeline, ONE barrier per K-step (issue-early/drain-late):
  // stage(t+1) is in flight during kstep(t)'s ds_read+MFMA; the barrier's
  // implicit vmcnt(0) drains it afterwards, and the same barrier protects
  // the buffer being overwritten next.
  stage(As0, Bs0, 0);
  __syncthreads();
  stage(As1, Bs1, 128);
  kstep(As0, Bs0);
  __syncthreads();
  stage(As0, Bs0, 256);
  kstep(As1, Bs1);
  __syncthreads();
  stage(As1, Bs1, 384);
  kstep(As0, Bs0);
  __syncthreads();
  kstep(As1, Bs1);

  if constexpr (MODE == 1 || MODE == 3) {
    #pragma unroll
    for (int mt = 0; mt < 4; ++mt) {
      const int row4 = m0 + wm * 64 + mt * 16 + kgrp * 4;
      const int token = row4 >> 2;
      float p0 = 0.f, p1 = 0.f, p2 = 0.f, p3 = 0.f;
      #pragma unroll
      for (int nt = 0; nt < 4; ++nt) {
        float e0 = __expf(acc[mt][nt][0] + bdec[nt]);
        float e1 = __expf(acc[mt][nt][1] + bdec[nt]);
        float e2 = __expf(acc[mt][nt][2] + bdec[nt]);
        float e3 = __expf(acc[mt][nt][3] + bdec[nt]);
        p0 += e0; p1 += e1; p2 += e2; p3 += e3;
        if constexpr (MODE == 3) {
          const int v = v0 + wn * 64 + nt * 16 + lrow;
          int u = 0;
          u = __builtin_amdgcn_cvt_pk_fp8_f32(e0, e1, u, false);
          u = __builtin_amdgcn_cvt_pk_fp8_f32(e2, e3, u, true);
          __builtin_nontemporal_store((unsigned int)u, &pbuf[(size_t)token * V_ + v]);
        }
      }
      #pragma unroll
      for (int off = 1; off < 16; off <<= 1) {
        p0 += __shfl_xor(p0, off);
        p1 += __shfl_xor(p1, off);
        p2 += __shfl_xor(p2, off);
        p3 += __shfl_xor(p3, off);
      }
      if (lrow == 0) {
        atomicAdd(&S[row4 + 0], p0);
        atomicAdd(&S[row4 + 1], p1);
        atomicAdd(&S[row4 + 2], p2);
        atomicAdd(&S[row4 + 3], p3);
      }
    }
  } else {  // MODE == 2
    #pragma unroll
    for (int mt = 0; mt < 4; ++mt) {
      const int row4 = m0 + wm * 64 + mt * 16 + kgrp * 4;
      const float4 qv = *(const float4*)&q[row4];
      const int token = row4 >> 2;
      #pragma unroll
      for (int nt = 0; nt < 4; ++nt) {
        float v = qv.x * __expf(acc[mt][nt][0] + bdec[nt]) +
                  qv.y * __expf(acc[mt][nt][1] + bdec[nt]) +
                  qv.z * __expf(acc[mt][nt][2] + bdec[nt]) +
                  qv.w * __expf(acc[mt][nt][3] + bdec[nt]);
        out[(size_t)token * V_ + v0 + wn * 64 + nt * 16 + lrow] = __logf(v);
      }
    }
  }
}

// ---- combine: out[t][v] = log(sum_e q_e * p8[t][v][e]) ----
__global__ __launch_bounds__(256) void combine_kernel(
    const unsigned int* __restrict__ pbuf,
    const float* __restrict__ lc, const float* __restrict__ S,
    float* __restrict__ out) {
  const int t = blockIdx.y;
  const int v = blockIdx.x * 1024 + threadIdx.x * 4;
  if (v >= V_) return;
  const float4 lcv = ((const float4*)lc)[t];
  const float4 Sv = ((const float4*)S)[t];
  const float q0 = __expf(lcv.x) / Sv.x;
  const float q1 = __expf(lcv.y) / Sv.y;
  const float q2 = __expf(lcv.z) / Sv.z;
  const float q3 = __expf(lcv.w) / Sv.w;
  u32x4 u = __builtin_nontemporal_load((const u32x4*)(pbuf + (size_t)t * V_ + v));
  float4 o;
  #pragma unroll
  for (int j = 0; j < 4; ++j) {
    unsigned int w = u[j];
    f32x2 lo = __builtin_amdgcn_cvt_pk_f32_fp8(w, false);
    f32x2 hi = __builtin_amdgcn_cvt_pk_f32_fp8(w, true);
    float s = q0 * lo.x + q1 * lo.y + q2 * hi.x + q3 * hi.y;
    ((float*)&o)[j] = __logf(s);
  }
  *(float4*)&out[(size_t)t * V_ + v] = o;
}

extern "C" void kernel_launch(void* const* d_in, const int* in_sizes, int n_in,
                              void* d_out, int out_size, void* d_ws, size_t ws_size,
                              hipStream_t stream) {
  const float* hs       = (const float*)d_in[0];
  const float* W_prior  = (const float*)d_in[1];
  const float* b_prior  = (const float*)d_in[2];
  const float* W_latent = (const float*)d_in[3];
  const float* b_latent = (const float*)d_in[4];
  const float* W_dec    = (const float*)d_in[5];
  const float* b_dec    = (const float*)d_in[6];
  float* out = (float*)d_out;

  char* ws = (char*)d_ws;
  __hip_bfloat16* hs_bf   = (__hip_bfloat16*)(ws);                    // 1 MB
  __hip_bfloat16* WlatT   = (__hip_bfloat16*)(ws + (1u << 20));       // 2 MB
  unsigned char*  latent8 = (unsigned char*)(ws + 3u * (1u << 20));   // 2 MB [4096][512]
  unsigned char*  WdecT8  = (unsigned char*)(ws + 5u * (1u << 20));   // 16.4 MB [32000][512]
  float* log_coef = (float*)(ws + 22u * (1u << 20));                  // 16 KB
  float* S = log_coef + AROWS;                                        // 16 KB
  float* q = S + AROWS;                                               // 16 KB
  unsigned int* pbuf = (unsigned int*)(ws + 23u * (1u << 20));        // 131 MB

  const size_t needA = 23u * (1u << 20) + (size_t)L_ * V_ * 4;
  const bool pathA = ws_size >= needA;

  prep_kernel<<<PREP_TOT, 256, 0, stream>>>(hs, W_prior, b_prior, W_latent, W_dec,
                                            hs_bf, WlatT, WdecT8, log_coef, S);
  latent_gemm<<<dim3((E_ * D_) / 128, L_ / 128), 256, 0, stream>>>(hs_bf, WlatT, b_latent, latent8);

  if (pathA) {
    mos_gemm<3><<<8 * 16 * 63, 256, 0, stream>>>(latent8, WdecT8, b_dec, nullptr, S, nullptr, pbuf);
    combine_kernel<<<dim3(32, L_), 256, 0, stream>>>(pbuf, log_coef, S, out);
  } else {
    mos_gemm<1><<<8 * 16 * 63, 256, 0, stream>>>(latent8, WdecT8, b_dec, nullptr, S, nullptr, nullptr);
    qk_kernel<<<(AROWS + 255) / 256, 256, 0, stream>>>(log_coef, S, q);
    mos_gemm<2><<<8 * 16 * 63, 256, 0, stream>>>(latent8, WdecT8, b_dec, q, nullptr, out, nullptr);
  }
}